// Round 6
// baseline (1565.154 us; speedup 1.0000x reference)
//
#include <hip/hip_runtime.h>

#define Bb 8
#define Nn 512
#define Ee 1024
#define Hh 128
#define Tt 8
#define FPAD 132

__device__ __forceinline__ float sigm(float x){ return 1.0f/(1.0f + __expf(-x)); }
__device__ __forceinline__ float tanh_fast(float x){ return 2.0f/(1.0f + __expf(-2.0f*x)) - 1.0f; }

__device__ __forceinline__ void fma4(float* acc, float4 x, float4 w0, float4 w1, float4 w2, float4 w3){
  acc[0] += x.x*w0.x + x.y*w1.x + x.z*w2.x + x.w*w3.x;
  acc[1] += x.x*w0.y + x.y*w1.y + x.z*w2.y + x.w*w3.y;
  acc[2] += x.x*w0.z + x.y*w1.z + x.z*w2.z + x.w*w3.z;
  acc[3] += x.x*w0.w + x.y*w1.w + x.z*w2.w + x.w*w3.w;
}

// Extract src/tgt indices from the dense one-hot incidence matrices.
__global__ void k_extract(const float4* __restrict__ n2e, const float4* __restrict__ e2n,
                          int* __restrict__ src, int* __restrict__ tgt){
  const int total1 = Bb*Ee*Nn/4;
  for (int i = blockIdx.x*blockDim.x + threadIdx.x; i < total1; i += gridDim.x*blockDim.x){
    float4 v = n2e[i];
    if (v.x!=0.f || v.y!=0.f || v.z!=0.f || v.w!=0.f){
      int base = i*4;
      int row = base >> 9;        // b*E + e   (N = 512)
      int n   = base & 511;
      if (v.x!=0.f) src[row] = n;
      if (v.y!=0.f) src[row] = n+1;
      if (v.z!=0.f) src[row] = n+2;
      if (v.w!=0.f) src[row] = n+3;
    }
  }
  const int total2 = Bb*Nn*Ee/4;
  for (int i = blockIdx.x*blockDim.x + threadIdx.x; i < total2; i += gridDim.x*blockDim.x){
    float4 v = e2n[i];
    if (v.x!=0.f || v.y!=0.f || v.z!=0.f || v.w!=0.f){
      int base = i*4;
      int row = base >> 10;       // b*N + n   (E = 1024)
      int e   = base & 1023;
      int b = row >> 9, n = row & 511;
      int* tp = tgt + b*Ee;
      if (v.x!=0.f) tp[e]   = n;
      if (v.y!=0.f) tp[e+1] = n;
      if (v.z!=0.f) tp[e+2] = n;
      if (v.w!=0.f) tp[e+3] = n;
    }
  }
}

// Transpose edge weights: W[t][h][d] -> WT[t][d][h]
__global__ void k_transW(const float* __restrict__ W, float* __restrict__ WT){
  int i = blockIdx.x*blockDim.x + threadIdx.x;
  if (i >= Tt*Hh*Hh) return;
  int t = i >> 14;
  int h = (i >> 7) & 127;
  int d = i & 127;
  WT[(t*Hh + d)*Hh + h] = W[i];
}

// Fold Wf: af = fw@(Wa+Wd) + bw@(Wb-Wd) + (fw*bw)@Wc   -> Ff[384][128]
__global__ void k_prep(const float* __restrict__ Wf, float* __restrict__ Ff){
  int i = blockIdx.x*blockDim.x + threadIdx.x;
  if (i >= 384*Hh) return;
  int r = i >> 7, c = i & 127;
  float v;
  if (r < 128)      v = Wf[r*Hh + c] + Wf[(r+384)*Hh + c];
  else if (r < 256) v = Wf[r*Hh + c] - Wf[(r+256)*Hh + c];
  else              v = Wf[r*Hh + c];
  Ff[i] = v;
}

// Per-graph counting sort of edges by type.
__global__ void k_sort(const int* __restrict__ ev, int* __restrict__ order, int* __restrict__ offs){
  __shared__ int cnt[Tt], offs_s[Tt+1], pos[Tt];
  int b = blockIdx.x, tid = threadIdx.x;
  if (tid < Tt) cnt[tid] = 0;
  __syncthreads();
  for (int e = tid; e < Ee; e += blockDim.x) atomicAdd(&cnt[ev[b*Ee+e]], 1);
  __syncthreads();
  if (tid == 0){ offs_s[0]=0; for (int t=0;t<Tt;t++) offs_s[t+1]=offs_s[t]+cnt[t]; }
  __syncthreads();
  if (tid < Tt) pos[tid] = offs_s[tid];
  if (tid < Tt+1) offs[b*(Tt+1)+tid] = offs_s[tid];
  __syncthreads();
  for (int e = tid; e < Ee; e += blockDim.x){
    int t = ev[b*Ee+e];
    int p = atomicAdd(&pos[t], 1);
    order[b*Ee + p] = e;
  }
}

// W loaders: k0 is compile-time after unroll; buffers stay in VGPRs (all-static indices).
__device__ __forceinline__ void ldw4(float4* b, const float* __restrict__ W, int k0){
  #pragma unroll
  for (int j = 0; j < 4; ++j) b[j] = *(const float4*)&W[(k0+j)*Hh];
}
__device__ __forceinline__ void ldw8(float4* b, const float* __restrict__ W, int k0){
  #pragma unroll
  for (int j = 0; j < 8; ++j) b[j] = *(const float4*)&W[(k0+j)*Hh];
}

// ------------- edge message passing v5: no LDS tile; W + X register pipeline -------------
// block = (b, t, dir) x chunk; 256 threads; thread = 4 edges x 4 cols.
// X gathered directly from global h (8 distinct rows per wave -> L1-resident lines).
__global__ __launch_bounds__(256) void k_edge_mp(
    const float* __restrict__ h, const float* __restrict__ WT,
    const int* __restrict__ order, const int* __restrict__ offs,
    const int* __restrict__ src, const int* __restrict__ tgt,
    float* __restrict__ bw, float* __restrict__ fw)
{
  int x = blockIdx.x;
  int dir = x & 1, bt = x >> 1, t = bt & 7, b = bt >> 3;
  int beg = offs[b*(Tt+1)+t], end = offs[b*(Tt+1)+t+1];
  int chunk0 = beg + blockIdx.y*32;
  if (chunk0 >= end) return;
  const int* gI = dir ? tgt : src;
  const int* sI = dir ? src : tgt;
  float* out = dir ? fw : bw;

  __shared__ int sGat[32];   // gather node id per edge slot
  __shared__ int sSc[32];    // scatter node id per edge slot
  int tid = threadIdx.x, lane = tid & 63, w = tid >> 6;
  int e0 = (lane >> 3)*4;
  int c0 = w*32 + (lane & 7)*4;
  const float* __restrict__ Wg = WT + t*Hh*Hh + c0;

  for (int chunk = chunk0; chunk < end; chunk += gridDim.y*32){
    int ne = min(32, end - chunk);
    __syncthreads();                    // protect sGat/sSc from prev iteration readers
    if (tid < 32){
      int ng = -1, ns = -1;
      if (tid < ne){
        int eid = order[b*Ee + chunk + tid];
        ng = gI[b*Ee + eid];
        ns = sI[b*Ee + eid];
      }
      sGat[tid] = ng; sSc[tid] = ns;
    }
    __syncthreads();

    const float* xr[4];
    int nsc[4];
    #pragma unroll
    for (int je = 0; je < 4; ++je){
      int ng = sGat[e0+je];
      xr[je] = h + (size_t)(b*Nn + (ng < 0 ? 0 : ng))*Hh;   // clamp: garbage acc never scattered
      nsc[je] = sSc[e0+je];
    }

    // K=128 in 32 stages of 4 k-rows, 1-stage lookahead, named A/B buffers (~96 VGPR live)
    float acc[4][4] = {};
    float4 wA[4], wB[4], xA[4], xB[4];
    ldw4(wA, Wg, 0);
    #pragma unroll
    for (int je = 0; je < 4; ++je) xA[je] = *(const float4*)&xr[je][0];
    #pragma unroll
    for (int s = 0; s < 32; s += 2){
      ldw4(wB, Wg, (s+1)*4);
      #pragma unroll
      for (int je = 0; je < 4; ++je) xB[je] = *(const float4*)&xr[je][(s+1)*4];
      #pragma unroll
      for (int je = 0; je < 4; ++je) fma4(acc[je], xA[je], wA[0], wA[1], wA[2], wA[3]);
      if (s+2 < 32){
        ldw4(wA, Wg, (s+2)*4);
        #pragma unroll
        for (int je = 0; je < 4; ++je) xA[je] = *(const float4*)&xr[je][(s+2)*4];
      }
      #pragma unroll
      for (int je = 0; je < 4; ++je) fma4(acc[je], xB[je], wB[0], wB[1], wB[2], wB[3]);
    }

    #pragma unroll
    for (int j = 0; j < 4; ++j){
      int node = nsc[j];
      if (node >= 0){
        float* op = out + (size_t)(b*Nn + node)*Hh + c0;
        atomicAdd(op+0, acc[j][0]);
        atomicAdd(op+1, acc[j][1]);
        atomicAdd(op+2, acc[j][2]);
        atomicAdd(op+3, acc[j][3]);
      }
    }
  }
}

// ------------- fused GatedFusion + GRU v5: X from global/L1, LDS only for agg/rh -------------
// 512 blocks x 256 threads; block = 8 rows x 128 cols; thread = 1 row x 4 cols.
// wave = 8 rows x 32 cols -> W read = 128 B/wave/k-row (minimal L2 stream).

// acc += xrow[0:128] @ W (W pre-offset by c0); stage = 8 k-rows, 1-stage lookahead.
__device__ __forceinline__ void sec_row(const float* __restrict__ xrow,
                                        const float* __restrict__ Wg, float* acc){
  float4 wA[8], wB[8], xA0, xA1, xB0, xB1;
  ldw8(wA, Wg, 0);
  xA0 = *(const float4*)&xrow[0]; xA1 = *(const float4*)&xrow[4];
  #pragma unroll
  for (int s = 0; s < 16; s += 2){
    ldw8(wB, Wg, (s+1)*8);
    xB0 = *(const float4*)&xrow[(s+1)*8]; xB1 = *(const float4*)&xrow[(s+1)*8+4];
    fma4(acc, xA0, wA[0], wA[1], wA[2], wA[3]);
    fma4(acc, xA1, wA[4], wA[5], wA[6], wA[7]);
    if (s+2 < 16){
      ldw8(wA, Wg, (s+2)*8);
      xA0 = *(const float4*)&xrow[(s+2)*8]; xA1 = *(const float4*)&xrow[(s+2)*8+4];
    }
    fma4(acc, xB0, wB[0], wB[1], wB[2], wB[3]);
    fma4(acc, xB1, wB[4], wB[5], wB[6], wB[7]);
  }
}

// acc += (a*b)[0:128] @ W
__device__ __forceinline__ void sec_prod(const float* __restrict__ ar_, const float* __restrict__ br_,
                                         const float* __restrict__ Wg, float* acc){
  float4 wA[8], wB[8];
  float4 xA0, xA1, xB0, xB1;
  ldw8(wA, Wg, 0);
  {
    float4 a0 = *(const float4*)&ar_[0], b0 = *(const float4*)&br_[0];
    float4 a1 = *(const float4*)&ar_[4], b1 = *(const float4*)&br_[4];
    xA0 = make_float4(a0.x*b0.x, a0.y*b0.y, a0.z*b0.z, a0.w*b0.w);
    xA1 = make_float4(a1.x*b1.x, a1.y*b1.y, a1.z*b1.z, a1.w*b1.w);
  }
  #pragma unroll
  for (int s = 0; s < 16; s += 2){
    ldw8(wB, Wg, (s+1)*8);
    {
      float4 a0 = *(const float4*)&ar_[(s+1)*8],   b0 = *(const float4*)&br_[(s+1)*8];
      float4 a1 = *(const float4*)&ar_[(s+1)*8+4], b1 = *(const float4*)&br_[(s+1)*8+4];
      xB0 = make_float4(a0.x*b0.x, a0.y*b0.y, a0.z*b0.z, a0.w*b0.w);
      xB1 = make_float4(a1.x*b1.x, a1.y*b1.y, a1.z*b1.z, a1.w*b1.w);
    }
    fma4(acc, xA0, wA[0], wA[1], wA[2], wA[3]);
    fma4(acc, xA1, wA[4], wA[5], wA[6], wA[7]);
    if (s+2 < 16){
      ldw8(wA, Wg, (s+2)*8);
      float4 a0 = *(const float4*)&ar_[(s+2)*8],   b0 = *(const float4*)&br_[(s+2)*8];
      float4 a1 = *(const float4*)&ar_[(s+2)*8+4], b1 = *(const float4*)&br_[(s+2)*8+4];
      xA0 = make_float4(a0.x*b0.x, a0.y*b0.y, a0.z*b0.z, a0.w*b0.w);
      xA1 = make_float4(a1.x*b1.x, a1.y*b1.y, a1.z*b1.z, a1.w*b1.w);
    }
    fma4(acc, xB0, wB[0], wB[1], wB[2], wB[3]);
    fma4(acc, xB1, wB[4], wB[5], wB[6], wB[7]);
  }
}

// acc1 += xrow @ Wa ; acc2 += xrow @ Wb ; stage = 4 k-rows (two W streams).
__device__ __forceinline__ void sec2(const float* __restrict__ xrow,
                                     const float* __restrict__ Wa, const float* __restrict__ Wc,
                                     float* acc1, float* acc2){
  float4 aA[4], aB[4], cA[4], cB[4], xA, xB;
  ldw4(aA, Wa, 0); ldw4(cA, Wc, 0);
  xA = *(const float4*)&xrow[0];
  #pragma unroll
  for (int s = 0; s < 32; s += 2){
    ldw4(aB, Wa, (s+1)*4); ldw4(cB, Wc, (s+1)*4);
    xB = *(const float4*)&xrow[(s+1)*4];
    fma4(acc1, xA, aA[0], aA[1], aA[2], aA[3]);
    fma4(acc2, xA, cA[0], cA[1], cA[2], cA[3]);
    if (s+2 < 32){
      ldw4(aA, Wa, (s+2)*4); ldw4(cA, Wc, (s+2)*4);
      xA = *(const float4*)&xrow[(s+2)*4];
    }
    fma4(acc1, xB, aB[0], aB[1], aB[2], aB[3]);
    fma4(acc2, xB, cB[0], cB[1], cB[2], cB[3]);
  }
}

__global__ __launch_bounds__(256) void k_fuse_gru(
    const float* __restrict__ hin, const float* __restrict__ fw, const float* __restrict__ bw,
    const float* __restrict__ Ff, const float* __restrict__ bfv,
    const float* __restrict__ Wz, const float* __restrict__ Wr, const float* __restrict__ Wt,
    float* __restrict__ hout, float* __restrict__ zf, float* __restrict__ zb)
{
  __shared__ float sA[8][FPAD];   // agg exchange
  __shared__ float sR[8][FPAD];   // r*h exchange
  int tid  = threadIdx.x;
  int row0 = blockIdx.x * 8;
  int lane = tid & 63, w = tid >> 6;
  int r    = lane >> 3;
  int c0   = w*32 + (lane & 7)*4;

  const float* __restrict__ frow = fw  + (size_t)(row0 + r)*Hh;
  const float* __restrict__ brow = bw  + (size_t)(row0 + r)*Hh;
  const float* __restrict__ hrow = hin + (size_t)(row0 + r)*Hh;
  float4 bias = *(const float4*)&bfv[c0];

  // ---- P1: af = fw@F0 + bw@F1 + (fw*bw)@F2 ----
  float af[4] = {0,0,0,0};
  sec_row (frow, Ff + c0,            af);
  sec_row (brow, Ff + 128*Hh + c0,   af);
  sec_prod(frow, brow, Ff + 256*Hh + c0, af);

  // agg = (1-z)*fw + z*bw  -> sA
  {
    float4 fv = *(const float4*)&frow[c0];
    float4 bv = *(const float4*)&brow[c0];
    float bb[4] = {bias.x, bias.y, bias.z, bias.w};
    float fvv[4] = {fv.x, fv.y, fv.z, fv.w};
    float bvv[4] = {bv.x, bv.y, bv.z, bv.w};
    float ag[4];
    #pragma unroll
    for (int j = 0; j < 4; ++j){
      float z = sigm(af[j] + bb[j]);
      ag[j] = (1.0f - z)*fvv[j] + z*bvv[j];
    }
    *(float4*)&sA[r][c0] = make_float4(ag[0], ag[1], ag[2], ag[3]);
  }

  // ---- P2: az/ar = [h|agg] @ Wz/Wr ---- (h-half overlaps the barrier)
  float az[4] = {0,0,0,0}, ar[4] = {0,0,0,0};
  sec2(hrow, Wz + c0, Wr + c0, az, ar);
  __syncthreads();                                   // sA (agg) visible
  sec2(&sA[r][0], Wz + 128*Hh + c0, Wr + 128*Hh + c0, az, ar);

  // rh = sigmoid(ar)*h -> sR ; keep z in regs
  float zz[4], hv[4];
  {
    float4 hv4 = *(const float4*)&hrow[c0];
    hv[0]=hv4.x; hv[1]=hv4.y; hv[2]=hv4.z; hv[3]=hv4.w;
    float rh[4];
    #pragma unroll
    for (int j = 0; j < 4; ++j){
      zz[j] = sigm(az[j]);
      rh[j] = sigm(ar[j]) * hv[j];
    }
    *(float4*)&sR[r][c0] = make_float4(rh[0], rh[1], rh[2], rh[3]);
  }

  // ---- P3: at = [rh|agg] @ Wt ---- (agg-half first, overlaps the barrier)
  float at[4] = {0,0,0,0};
  sec_row(&sA[r][0], Wt + 128*Hh + c0, at);
  __syncthreads();                                   // sR (rh) visible
  sec_row(&sR[r][0], Wt + c0, at);

  float o[4];
  #pragma unroll
  for (int j = 0; j < 4; ++j){
    float t = tanh_fast(at[j]);
    o[j] = (1.0f - zz[j])*hv[j] + zz[j]*t;
  }
  *(float4*)&hout[(size_t)(row0 + r)*Hh + c0] = make_float4(o[0], o[1], o[2], o[3]);

  // zero fw/bw rows for the next hop (all fw/bw reads are above; block-private rows)
  {
    int ir = tid >> 5, k0 = (tid & 31)*4;
    size_t g = (size_t)(row0 + ir)*Hh + k0;
    float4 zv = {0.f,0.f,0.f,0.f};
    *(float4*)&zf[g] = zv;
    *(float4*)&zb[g] = zv;
  }
}

extern "C" void kernel_launch(void* const* d_in, const int* in_sizes, int n_in,
                              void* d_out, int out_size, void* d_ws, size_t ws_size,
                              hipStream_t stream){
  const float* node_feature = (const float*)d_in[0];
  const int*   edge_vec     = (const int*)d_in[1];
  const float* n2e          = (const float*)d_in[2];
  const float* e2n          = (const float*)d_in[3];
  const float* Wtensor      = (const float*)d_in[4];
  const float* Wz           = (const float*)d_in[5];
  const float* Wr           = (const float*)d_in[6];
  const float* Wt           = (const float*)d_in[7];
  const float* Wf           = (const float*)d_in[8];
  const float* bf           = (const float*)d_in[9];
  float* out = (float*)d_out;

  char* p = (char*)d_ws;
  int* src   = (int*)p; p += Bb*Ee*4;
  int* tgt   = (int*)p; p += Bb*Ee*4;
  int* order = (int*)p; p += Bb*Ee*4;
  int* offs  = (int*)p; p += 4096;
  float* WT  = (float*)p; p += (size_t)Tt*Hh*Hh*4;
  float* Ff  = (float*)p; p += (size_t)384*Hh*4;
  float* bwp = (float*)p; p += (size_t)Bb*Nn*Hh*4;
  float* fwp = (float*)p; p += (size_t)Bb*Nn*Hh*4;
  float* h1  = (float*)p; p += (size_t)Bb*Nn*Hh*4;

  k_extract<<<1024, 256, 0, stream>>>((const float4*)n2e, (const float4*)e2n, src, tgt);
  k_transW<<<(Tt*Hh*Hh + 255)/256, 256, 0, stream>>>(Wtensor, WT);
  k_prep<<<(384*Hh + 255)/256, 256, 0, stream>>>(Wf, Ff);
  k_sort<<<Bb, 256, 0, stream>>>(edge_vec, order, offs);
  hipMemsetAsync(bwp, 0, (size_t)2*Bb*Nn*Hh*4, stream);   // bw+fw zero (hops re-zero in epilogue)

  const float* hin = node_feature;
  float* houts[3] = { out, h1, out };
  for (int hop = 0; hop < 3; ++hop){
    k_edge_mp<<<dim3(Bb*Tt*2, 4), 256, 0, stream>>>(hin, WT, order, offs, src, tgt, bwp, fwp);
    k_fuse_gru<<<(Bb*Nn)/8, 256, 0, stream>>>(hin, fwp, bwp, Ff, bf, Wz, Wr, Wt, houts[hop], fwp, bwp);
    hin = houts[hop];
  }
}

// Round 7
// 499.366 us; speedup vs baseline: 3.1343x; 3.1343x over previous
//
#include <hip/hip_runtime.h>

#define Bb 8
#define Nn 512
#define Ee 1024
#define Hh 128
#define Tt 8
#define FPAD 132

__device__ __forceinline__ float sigm(float x){ return 1.0f/(1.0f + __expf(-x)); }
__device__ __forceinline__ float tanh_fast(float x){ return 2.0f/(1.0f + __expf(-2.0f*x)) - 1.0f; }

__device__ __forceinline__ void fma4(float* acc, float4 x, float4 w0, float4 w1, float4 w2, float4 w3){
  acc[0] += x.x*w0.x + x.y*w1.x + x.z*w2.x + x.w*w3.x;
  acc[1] += x.x*w0.y + x.y*w1.y + x.z*w2.y + x.w*w3.y;
  acc[2] += x.x*w0.z + x.y*w1.z + x.z*w2.z + x.w*w3.z;
  acc[3] += x.x*w0.w + x.y*w1.w + x.z*w2.w + x.w*w3.w;
}

// Extract src/tgt indices from the dense one-hot incidence matrices.
__global__ void k_extract(const float4* __restrict__ n2e, const float4* __restrict__ e2n,
                          int* __restrict__ src, int* __restrict__ tgt){
  const int total1 = Bb*Ee*Nn/4;
  for (int i = blockIdx.x*blockDim.x + threadIdx.x; i < total1; i += gridDim.x*blockDim.x){
    float4 v = n2e[i];
    if (v.x!=0.f || v.y!=0.f || v.z!=0.f || v.w!=0.f){
      int base = i*4;
      int row = base >> 9;        // b*E + e   (N = 512)
      int n   = base & 511;
      if (v.x!=0.f) src[row] = n;
      if (v.y!=0.f) src[row] = n+1;
      if (v.z!=0.f) src[row] = n+2;
      if (v.w!=0.f) src[row] = n+3;
    }
  }
  const int total2 = Bb*Nn*Ee/4;
  for (int i = blockIdx.x*blockDim.x + threadIdx.x; i < total2; i += gridDim.x*blockDim.x){
    float4 v = e2n[i];
    if (v.x!=0.f || v.y!=0.f || v.z!=0.f || v.w!=0.f){
      int base = i*4;
      int row = base >> 10;       // b*N + n   (E = 1024)
      int e   = base & 1023;
      int b = row >> 9, n = row & 511;
      int* tp = tgt + b*Ee;
      if (v.x!=0.f) tp[e]   = n;
      if (v.y!=0.f) tp[e+1] = n;
      if (v.z!=0.f) tp[e+2] = n;
      if (v.w!=0.f) tp[e+3] = n;
    }
  }
}

// Transpose edge weights: W[t][h][d] -> WT[t][d][h]
__global__ void k_transW(const float* __restrict__ W, float* __restrict__ WT){
  int i = blockIdx.x*blockDim.x + threadIdx.x;
  if (i >= Tt*Hh*Hh) return;
  int t = i >> 14;
  int h = (i >> 7) & 127;
  int d = i & 127;
  WT[(t*Hh + d)*Hh + h] = W[i];
}

// Fold Wf: af = fw@(Wa+Wd) + bw@(Wb-Wd) + (fw*bw)@Wc   -> Ff[384][128]
__global__ void k_prep(const float* __restrict__ Wf, float* __restrict__ Ff){
  int i = blockIdx.x*blockDim.x + threadIdx.x;
  if (i >= 384*Hh) return;
  int r = i >> 7, c = i & 127;
  float v;
  if (r < 128)      v = Wf[r*Hh + c] + Wf[(r+384)*Hh + c];
  else if (r < 256) v = Wf[r*Hh + c] - Wf[(r+256)*Hh + c];
  else              v = Wf[r*Hh + c];
  Ff[i] = v;
}

// Per-graph counting sort of edges by type.
__global__ void k_sort(const int* __restrict__ ev, int* __restrict__ order, int* __restrict__ offs){
  __shared__ int cnt[Tt], offs_s[Tt+1], pos[Tt];
  int b = blockIdx.x, tid = threadIdx.x;
  if (tid < Tt) cnt[tid] = 0;
  __syncthreads();
  for (int e = tid; e < Ee; e += blockDim.x) atomicAdd(&cnt[ev[b*Ee+e]], 1);
  __syncthreads();
  if (tid == 0){ offs_s[0]=0; for (int t=0;t<Tt;t++) offs_s[t+1]=offs_s[t]+cnt[t]; }
  __syncthreads();
  if (tid < Tt) pos[tid] = offs_s[tid];
  if (tid < Tt+1) offs[b*(Tt+1)+tid] = offs_s[tid];
  __syncthreads();
  for (int e = tid; e < Ee; e += blockDim.x){
    int t = ev[b*Ee+e];
    int p = atomicAdd(&pos[t], 1);
    order[b*Ee + p] = e;
  }
}

// runtime-k W loader (k0 is a rolled loop variable -> no compile-time hoisting)
__device__ __forceinline__ void ldw4(float4* b, const float* __restrict__ W, int k0){
  #pragma unroll
  for (int j = 0; j < 4; ++j) b[j] = *(const float4*)&W[(size_t)(k0+j)*Hh];
}

// ------------- edge message passing v6: rolled 2-stage pipeline, VGPR-capped -------------
// block = (b, t, dir) x chunk; 256 threads; thread = 4 edges x 4 cols.
__global__ __launch_bounds__(256, 4) void k_edge_mp(
    const float* __restrict__ h, const float* __restrict__ WT,
    const int* __restrict__ order, const int* __restrict__ offs,
    const int* __restrict__ src, const int* __restrict__ tgt,
    float* __restrict__ bw, float* __restrict__ fw)
{
  int x = blockIdx.x;
  int dir = x & 1, bt = x >> 1, t = bt & 7, b = bt >> 3;
  int beg = offs[b*(Tt+1)+t], end = offs[b*(Tt+1)+t+1];
  int chunk0 = beg + blockIdx.y*32;
  if (chunk0 >= end) return;
  const int* gI = dir ? tgt : src;
  const int* sI = dir ? src : tgt;
  float* out = dir ? fw : bw;

  __shared__ int sGat[32];
  __shared__ int sSc[32];
  int tid = threadIdx.x, lane = tid & 63, w = tid >> 6;
  int e0 = (lane >> 3)*4;
  int c0 = w*32 + (lane & 7)*4;
  const float* __restrict__ Wg = WT + t*Hh*Hh + c0;
  const int rot = ((blockIdx.x + blockIdx.y) & 7) * 16;   // L2 de-hotspot stagger

  for (int chunk = chunk0; chunk < end; chunk += gridDim.y*32){
    int ne = min(32, end - chunk);
    __syncthreads();
    if (tid < 32){
      int ng = -1, ns = -1;
      if (tid < ne){
        int eid = order[b*Ee + chunk + tid];
        ng = gI[b*Ee + eid];
        ns = sI[b*Ee + eid];
      }
      sGat[tid] = ng; sSc[tid] = ns;
    }
    __syncthreads();

    const float* xr[4];
    int nsc[4];
    #pragma unroll
    for (int je = 0; je < 4; ++je){
      int ng = sGat[e0+je];
      xr[je] = h + (size_t)(b*Nn + (ng < 0 ? 0 : ng))*Hh;
      nsc[je] = sSc[e0+je];
    }

    // K=128: rolled ping-pong, 4 k-rows/stage, 2 stages in flight, rotated start.
    float acc[4][4] = {};
    float4 wA[4], wB[4], xA[4], xB[4];
    int k0 = rot;
    ldw4(wA, Wg, k0);
    #pragma unroll
    for (int je = 0; je < 4; ++je) xA[je] = *(const float4*)&xr[je][k0];
    #pragma unroll 1
    for (int it = 0; it < 16; ++it){
      int k1 = (k0 + 4) & 127, k2 = (k0 + 8) & 127;
      ldw4(wB, Wg, k1);
      #pragma unroll
      for (int je = 0; je < 4; ++je) xB[je] = *(const float4*)&xr[je][k1];
      #pragma unroll
      for (int je = 0; je < 4; ++je) fma4(acc[je], xA[je], wA[0], wA[1], wA[2], wA[3]);
      ldw4(wA, Wg, k2);                      // last iter wraps to rot (in-bounds, unused)
      #pragma unroll
      for (int je = 0; je < 4; ++je) xA[je] = *(const float4*)&xr[je][k2];
      #pragma unroll
      for (int je = 0; je < 4; ++je) fma4(acc[je], xB[je], wB[0], wB[1], wB[2], wB[3]);
      k0 = k2;
    }

    #pragma unroll
    for (int j = 0; j < 4; ++j){
      int node = nsc[j];
      if (node >= 0){
        float* op = out + (size_t)(b*Nn + node)*Hh + c0;
        atomicAdd(op+0, acc[j][0]);
        atomicAdd(op+1, acc[j][1]);
        atomicAdd(op+2, acc[j][2]);
        atomicAdd(op+3, acc[j][3]);
      }
    }
  }
}

// ------------- fused GatedFusion + GRU v6: rolled pipelines, VGPR-capped, rotated k -------------
// 512 blocks x 256 threads; block = 8 rows x 128 cols; thread = 1 row x 4 cols.

// acc += xrow[0:128] @ W   (rolled ping-pong, 4 k-rows/stage)
__device__ __forceinline__ void sec_row(const float* __restrict__ xrow,
                                        const float* __restrict__ Wg, int rot, float* acc){
  float4 wA[4], wB[4], xA, xB;
  int k0 = rot;
  ldw4(wA, Wg, k0);
  xA = *(const float4*)&xrow[k0];
  #pragma unroll 1
  for (int it = 0; it < 16; ++it){
    int k1 = (k0 + 4) & 127, k2 = (k0 + 8) & 127;
    ldw4(wB, Wg, k1);
    xB = *(const float4*)&xrow[k1];
    fma4(acc, xA, wA[0], wA[1], wA[2], wA[3]);
    ldw4(wA, Wg, k2);
    xA = *(const float4*)&xrow[k2];
    fma4(acc, xB, wB[0], wB[1], wB[2], wB[3]);
    k0 = k2;
  }
}

// acc += (a*b)[0:128] @ W
__device__ __forceinline__ void sec_prod(const float* __restrict__ a_, const float* __restrict__ b_,
                                         const float* __restrict__ Wg, int rot, float* acc){
  float4 wA[4], wB[4], xA, xB;
  int k0 = rot;
  ldw4(wA, Wg, k0);
  { float4 av = *(const float4*)&a_[k0], bv = *(const float4*)&b_[k0];
    xA = make_float4(av.x*bv.x, av.y*bv.y, av.z*bv.z, av.w*bv.w); }
  #pragma unroll 1
  for (int it = 0; it < 16; ++it){
    int k1 = (k0 + 4) & 127, k2 = (k0 + 8) & 127;
    ldw4(wB, Wg, k1);
    { float4 av = *(const float4*)&a_[k1], bv = *(const float4*)&b_[k1];
      xB = make_float4(av.x*bv.x, av.y*bv.y, av.z*bv.z, av.w*bv.w); }
    fma4(acc, xA, wA[0], wA[1], wA[2], wA[3]);
    ldw4(wA, Wg, k2);
    { float4 av = *(const float4*)&a_[k2], bv = *(const float4*)&b_[k2];
      xA = make_float4(av.x*bv.x, av.y*bv.y, av.z*bv.z, av.w*bv.w); }
    fma4(acc, xB, wB[0], wB[1], wB[2], wB[3]);
    k0 = k2;
  }
}

// acc1 += xrow @ Wa ; acc2 += xrow @ Wc   (two W streams, shared X)
__device__ __forceinline__ void sec2(const float* __restrict__ xrow,
                                     const float* __restrict__ Wa, const float* __restrict__ Wc,
                                     int rot, float* acc1, float* acc2){
  float4 aA[4], aB[4], cA[4], cB[4], xA, xB;
  int k0 = rot;
  ldw4(aA, Wa, k0); ldw4(cA, Wc, k0);
  xA = *(const float4*)&xrow[k0];
  #pragma unroll 1
  for (int it = 0; it < 16; ++it){
    int k1 = (k0 + 4) & 127, k2 = (k0 + 8) & 127;
    ldw4(aB, Wa, k1); ldw4(cB, Wc, k1);
    xB = *(const float4*)&xrow[k1];
    fma4(acc1, xA, aA[0], aA[1], aA[2], aA[3]);
    fma4(acc2, xA, cA[0], cA[1], cA[2], cA[3]);
    ldw4(aA, Wa, k2); ldw4(cA, Wc, k2);
    xA = *(const float4*)&xrow[k2];
    fma4(acc1, xB, aB[0], aB[1], aB[2], aB[3]);
    fma4(acc2, xB, cB[0], cB[1], cB[2], cB[3]);
    k0 = k2;
  }
}

__global__ __launch_bounds__(256, 4) void k_fuse_gru(
    const float* __restrict__ hin, const float* __restrict__ fw, const float* __restrict__ bw,
    const float* __restrict__ Ff, const float* __restrict__ bfv,
    const float* __restrict__ Wz, const float* __restrict__ Wr, const float* __restrict__ Wt,
    float* __restrict__ hout, float* __restrict__ zf, float* __restrict__ zb)
{
  __shared__ float sA[8][FPAD];   // agg exchange
  __shared__ float sR[8][FPAD];   // r*h exchange
  int tid  = threadIdx.x;
  int row0 = blockIdx.x * 8;
  int lane = tid & 63, w = tid >> 6;
  int r    = lane >> 3;
  int c0   = w*32 + (lane & 7)*4;
  const int rot = (blockIdx.x & 7) * 16;   // L2 de-hotspot stagger

  const float* __restrict__ frow = fw  + (size_t)(row0 + r)*Hh;
  const float* __restrict__ brow = bw  + (size_t)(row0 + r)*Hh;
  const float* __restrict__ hrow = hin + (size_t)(row0 + r)*Hh;
  float4 bias = *(const float4*)&bfv[c0];

  // ---- P1: af = fw@F0 + bw@F1 + (fw*bw)@F2 ----
  float af[4] = {0,0,0,0};
  sec_row (frow, Ff + c0,              rot, af);
  sec_row (brow, Ff + 128*Hh + c0,     rot, af);
  sec_prod(frow, brow, Ff + 256*Hh + c0, rot, af);

  // agg = (1-z)*fw + z*bw  -> sA
  {
    float4 fv = *(const float4*)&frow[c0];
    float4 bv = *(const float4*)&brow[c0];
    float bb[4] = {bias.x, bias.y, bias.z, bias.w};
    float fvv[4] = {fv.x, fv.y, fv.z, fv.w};
    float bvv[4] = {bv.x, bv.y, bv.z, bv.w};
    float ag[4];
    #pragma unroll
    for (int j = 0; j < 4; ++j){
      float z = sigm(af[j] + bb[j]);
      ag[j] = (1.0f - z)*fvv[j] + z*bvv[j];
    }
    *(float4*)&sA[r][c0] = make_float4(ag[0], ag[1], ag[2], ag[3]);
  }

  // ---- P2: az/ar = [h|agg] @ Wz/Wr ---- (h-half overlaps the barrier)
  float az[4] = {0,0,0,0}, ar[4] = {0,0,0,0};
  sec2(hrow, Wz + c0, Wr + c0, rot, az, ar);
  __syncthreads();                                   // sA (agg) visible
  sec2(&sA[r][0], Wz + 128*Hh + c0, Wr + 128*Hh + c0, rot, az, ar);

  // rh = sigmoid(ar)*h -> sR ; keep z in regs
  float zz[4], hv[4];
  {
    float4 hv4 = *(const float4*)&hrow[c0];
    hv[0]=hv4.x; hv[1]=hv4.y; hv[2]=hv4.z; hv[3]=hv4.w;
    float rh[4];
    #pragma unroll
    for (int j = 0; j < 4; ++j){
      zz[j] = sigm(az[j]);
      rh[j] = sigm(ar[j]) * hv[j];
    }
    *(float4*)&sR[r][c0] = make_float4(rh[0], rh[1], rh[2], rh[3]);
  }

  // ---- P3: at = [rh|agg] @ Wt ---- (agg-half first, overlaps the barrier)
  float at[4] = {0,0,0,0};
  sec_row(&sA[r][0], Wt + 128*Hh + c0, rot, at);
  __syncthreads();                                   // sR (rh) visible
  sec_row(&sR[r][0], Wt + c0, rot, at);

  float o[4];
  #pragma unroll
  for (int j = 0; j < 4; ++j){
    float t = tanh_fast(at[j]);
    o[j] = (1.0f - zz[j])*hv[j] + zz[j]*t;
  }
  *(float4*)&hout[(size_t)(row0 + r)*Hh + c0] = make_float4(o[0], o[1], o[2], o[3]);

  // zero fw/bw rows for the next hop
  {
    int ir = tid >> 5, k0 = (tid & 31)*4;
    size_t g = (size_t)(row0 + ir)*Hh + k0;
    float4 zv = {0.f,0.f,0.f,0.f};
    *(float4*)&zf[g] = zv;
    *(float4*)&zb[g] = zv;
  }
}

extern "C" void kernel_launch(void* const* d_in, const int* in_sizes, int n_in,
                              void* d_out, int out_size, void* d_ws, size_t ws_size,
                              hipStream_t stream){
  const float* node_feature = (const float*)d_in[0];
  const int*   edge_vec     = (const int*)d_in[1];
  const float* n2e          = (const float*)d_in[2];
  const float* e2n          = (const float*)d_in[3];
  const float* Wtensor      = (const float*)d_in[4];
  const float* Wz           = (const float*)d_in[5];
  const float* Wr           = (const float*)d_in[6];
  const float* Wt           = (const float*)d_in[7];
  const float* Wf           = (const float*)d_in[8];
  const float* bf           = (const float*)d_in[9];
  float* out = (float*)d_out;

  char* p = (char*)d_ws;
  int* src   = (int*)p; p += Bb*Ee*4;
  int* tgt   = (int*)p; p += Bb*Ee*4;
  int* order = (int*)p; p += Bb*Ee*4;
  int* offs  = (int*)p; p += 4096;
  float* WT  = (float*)p; p += (size_t)Tt*Hh*Hh*4;
  float* Ff  = (float*)p; p += (size_t)384*Hh*4;
  float* bwp = (float*)p; p += (size_t)Bb*Nn*Hh*4;
  float* fwp = (float*)p; p += (size_t)Bb*Nn*Hh*4;
  float* h1  = (float*)p; p += (size_t)Bb*Nn*Hh*4;

  k_extract<<<1024, 256, 0, stream>>>((const float4*)n2e, (const float4*)e2n, src, tgt);
  k_transW<<<(Tt*Hh*Hh + 255)/256, 256, 0, stream>>>(Wtensor, WT);
  k_prep<<<(384*Hh + 255)/256, 256, 0, stream>>>(Wf, Ff);
  k_sort<<<Bb, 256, 0, stream>>>(edge_vec, order, offs);
  hipMemsetAsync(bwp, 0, (size_t)2*Bb*Nn*Hh*4, stream);   // bw+fw zero (hops re-zero in epilogue)

  const float* hin = node_feature;
  float* houts[3] = { out, h1, out };
  for (int hop = 0; hop < 3; ++hop){
    k_edge_mp<<<dim3(Bb*Tt*2, 4), 256, 0, stream>>>(hin, WT, order, offs, src, tgt, bwp, fwp);
    k_fuse_gru<<<(Bb*Nn)/8, 256, 0, stream>>>(hin, fwp, bwp, Ff, bf, Wz, Wr, Wt, houts[hop], fwp, bwp);
    hin = houts[hop];
  }
}

// Round 11
// 498.542 us; speedup vs baseline: 3.1395x; 1.0017x over previous
//
#include <hip/hip_runtime.h>

#define Bb 8
#define Nn 512
#define Ee 1024
#define Hh 128
#define Tt 8
#define FPAD 132

__device__ __forceinline__ float sigm(float x){ return 1.0f/(1.0f + __expf(-x)); }
__device__ __forceinline__ float tanh_fast(float x){ return 2.0f/(1.0f + __expf(-2.0f*x)) - 1.0f; }

__device__ __forceinline__ void fma4(float* acc, float4 x, float4 w0, float4 w1, float4 w2, float4 w3){
  acc[0] += x.x*w0.x + x.y*w1.x + x.z*w2.x + x.w*w3.x;
  acc[1] += x.x*w0.y + x.y*w1.y + x.z*w2.y + x.w*w3.y;
  acc[2] += x.x*w0.z + x.y*w1.z + x.z*w2.z + x.w*w3.z;
  acc[3] += x.x*w0.w + x.y*w1.w + x.z*w2.w + x.w*w3.w;
}

// Extract src/tgt indices from the dense one-hot incidence matrices.
__global__ void k_extract(const float4* __restrict__ n2e, const float4* __restrict__ e2n,
                          int* __restrict__ src, int* __restrict__ tgt){
  const int total1 = Bb*Ee*Nn/4;
  for (int i = blockIdx.x*blockDim.x + threadIdx.x; i < total1; i += gridDim.x*blockDim.x){
    float4 v = n2e[i];
    if (v.x!=0.f || v.y!=0.f || v.z!=0.f || v.w!=0.f){
      int base = i*4;
      int row = base >> 9;        // b*E + e   (N = 512)
      int n   = base & 511;
      if (v.x!=0.f) src[row] = n;
      if (v.y!=0.f) src[row] = n+1;
      if (v.z!=0.f) src[row] = n+2;
      if (v.w!=0.f) src[row] = n+3;
    }
  }
  const int total2 = Bb*Nn*Ee/4;
  for (int i = blockIdx.x*blockDim.x + threadIdx.x; i < total2; i += gridDim.x*blockDim.x){
    float4 v = e2n[i];
    if (v.x!=0.f || v.y!=0.f || v.z!=0.f || v.w!=0.f){
      int base = i*4;
      int row = base >> 10;       // b*N + n   (E = 1024)
      int e   = base & 1023;
      int b = row >> 9, n = row & 511;
      int* tp = tgt + b*Ee;
      if (v.x!=0.f) tp[e]   = n;
      if (v.y!=0.f) tp[e+1] = n;
      if (v.z!=0.f) tp[e+2] = n;
      if (v.w!=0.f) tp[e+3] = n;
    }
  }
}

// Transpose edge weights: W[t][h][d] -> WT[t][d][h]
__global__ void k_transW(const float* __restrict__ W, float* __restrict__ WT){
  int i = blockIdx.x*blockDim.x + threadIdx.x;
  if (i >= Tt*Hh*Hh) return;
  int t = i >> 14;
  int h = (i >> 7) & 127;
  int d = i & 127;
  WT[(t*Hh + d)*Hh + h] = W[i];
}

// Fold Wf: af = fw@(Wa+Wd) + bw@(Wb-Wd) + (fw*bw)@Wc   -> Ff[384][128]
__global__ void k_prep(const float* __restrict__ Wf, float* __restrict__ Ff){
  int i = blockIdx.x*blockDim.x + threadIdx.x;
  if (i >= 384*Hh) return;
  int r = i >> 7, c = i & 127;
  float v;
  if (r < 128)      v = Wf[r*Hh + c] + Wf[(r+384)*Hh + c];
  else if (r < 256) v = Wf[r*Hh + c] - Wf[(r+256)*Hh + c];
  else              v = Wf[r*Hh + c];
  Ff[i] = v;
}

// Per-graph counting sort of edges by type.
__global__ void k_sort(const int* __restrict__ ev, int* __restrict__ order, int* __restrict__ offs){
  __shared__ int cnt[Tt], offs_s[Tt+1], pos[Tt];
  int b = blockIdx.x, tid = threadIdx.x;
  if (tid < Tt) cnt[tid] = 0;
  __syncthreads();
  for (int e = tid; e < Ee; e += blockDim.x) atomicAdd(&cnt[ev[b*Ee+e]], 1);
  __syncthreads();
  if (tid == 0){ offs_s[0]=0; for (int t=0;t<Tt;t++) offs_s[t+1]=offs_s[t]+cnt[t]; }
  __syncthreads();
  if (tid < Tt) pos[tid] = offs_s[tid];
  if (tid < Tt+1) offs[b*(Tt+1)+tid] = offs_s[tid];
  __syncthreads();
  for (int e = tid; e < Ee; e += blockDim.x){
    int t = ev[b*Ee+e];
    int p = atomicAdd(&pos[t], 1);
    order[b*Ee + p] = e;
  }
}

// ---- plain unroll-4 GEMM sections over a 64-row K-half (R3 style; compiler schedules) ----
// acc(4 cols) += x[ko..ko+64) @ W[ko..ko+64)[c0..c0+4)   (W pre-offset by c0)
__device__ __forceinline__ void sec64(const float* __restrict__ x, const float* __restrict__ Wg,
                                      int ko, float* acc){
  #pragma unroll 4
  for (int k = 0; k < 64; k += 4){
    int kk = ko + k;
    float4 xv = *(const float4*)&x[kk];
    float4 w0 = *(const float4*)&Wg[(size_t)(kk+0)*Hh];
    float4 w1 = *(const float4*)&Wg[(size_t)(kk+1)*Hh];
    float4 w2 = *(const float4*)&Wg[(size_t)(kk+2)*Hh];
    float4 w3 = *(const float4*)&Wg[(size_t)(kk+3)*Hh];
    fma4(acc, xv, w0, w1, w2, w3);
  }
}

// acc += (a*b)[ko..ko+64) @ W
__device__ __forceinline__ void prod64(const float* __restrict__ a_, const float* __restrict__ b_,
                                       const float* __restrict__ Wg, int ko, float* acc){
  #pragma unroll 4
  for (int k = 0; k < 64; k += 4){
    int kk = ko + k;
    float4 av = *(const float4*)&a_[kk];
    float4 bv = *(const float4*)&b_[kk];
    float4 xv = make_float4(av.x*bv.x, av.y*bv.y, av.z*bv.z, av.w*bv.w);
    float4 w0 = *(const float4*)&Wg[(size_t)(kk+0)*Hh];
    float4 w1 = *(const float4*)&Wg[(size_t)(kk+1)*Hh];
    float4 w2 = *(const float4*)&Wg[(size_t)(kk+2)*Hh];
    float4 w3 = *(const float4*)&Wg[(size_t)(kk+3)*Hh];
    fma4(acc, xv, w0, w1, w2, w3);
  }
}

// acc1 += x @ Wa ; acc2 += x @ Wc over the K-half (shared x)
__device__ __forceinline__ void sec2_64(const float* __restrict__ x,
                                        const float* __restrict__ Wa, const float* __restrict__ Wc,
                                        int ko, float* acc1, float* acc2){
  #pragma unroll 2
  for (int k = 0; k < 64; k += 4){
    int kk = ko + k;
    float4 xv = *(const float4*)&x[kk];
    float4 a0 = *(const float4*)&Wa[(size_t)(kk+0)*Hh];
    float4 a1 = *(const float4*)&Wa[(size_t)(kk+1)*Hh];
    float4 a2 = *(const float4*)&Wa[(size_t)(kk+2)*Hh];
    float4 a3 = *(const float4*)&Wa[(size_t)(kk+3)*Hh];
    fma4(acc1, xv, a0, a1, a2, a3);
    float4 c0_ = *(const float4*)&Wc[(size_t)(kk+0)*Hh];
    float4 c1_ = *(const float4*)&Wc[(size_t)(kk+1)*Hh];
    float4 c2_ = *(const float4*)&Wc[(size_t)(kk+2)*Hh];
    float4 c3_ = *(const float4*)&Wc[(size_t)(kk+3)*Hh];
    fma4(acc2, xv, c0_, c1_, c2_, c3_);
  }
}

// ------------- edge message passing v7: 16-edge chunks, 2 edges x 4 cols/thread -------------
// grid = (128 bt-dir, 8 chunks); 1024 blocks -> 4 blocks/CU, 16 waves/CU.
__global__ __launch_bounds__(256, 4) void k_edge_mp(
    const float* __restrict__ h, const float* __restrict__ WT,
    const int* __restrict__ order, const int* __restrict__ offs,
    const int* __restrict__ src, const int* __restrict__ tgt,
    float* __restrict__ bw, float* __restrict__ fw)
{
  int x = blockIdx.x;
  int dir = x & 1, bt = x >> 1, t = bt & 7, b = bt >> 3;
  int beg = offs[b*(Tt+1)+t], end = offs[b*(Tt+1)+t+1];
  int chunk0 = beg + blockIdx.y*16;
  if (chunk0 >= end) return;
  const int* gI = dir ? tgt : src;
  const int* sI = dir ? src : tgt;
  float* out = dir ? fw : bw;

  __shared__ int sGat[16];
  __shared__ int sSc[16];
  int tid = threadIdx.x, lane = tid & 63, w = tid >> 6;
  int e0 = (lane >> 3)*2;               // 2 edges per 8-lane group
  int c0 = w*32 + (lane & 7)*4;
  const float* __restrict__ Wg = WT + t*Hh*Hh + c0;

  for (int chunk = chunk0; chunk < end; chunk += gridDim.y*16){
    int ne = min(16, end - chunk);
    __syncthreads();
    if (tid < 16){
      int ng = -1, ns = -1;
      if (tid < ne){
        int eid = order[b*Ee + chunk + tid];
        ng = gI[b*Ee + eid];
        ns = sI[b*Ee + eid];
      }
      sGat[tid] = ng; sSc[tid] = ns;
    }
    __syncthreads();

    const float* xr[2];
    int nsc[2];
    #pragma unroll
    for (int je = 0; je < 2; ++je){
      int ng = sGat[e0+je];
      xr[je] = h + (size_t)(b*Nn + (ng < 0 ? 0 : ng))*Hh;
      nsc[je] = sSc[e0+je];
    }

    float acc[2][4] = {};
    #pragma unroll 4
    for (int k = 0; k < Hh; k += 4){
      float4 w0 = *(const float4*)&Wg[(size_t)(k+0)*Hh];
      float4 w1 = *(const float4*)&Wg[(size_t)(k+1)*Hh];
      float4 w2 = *(const float4*)&Wg[(size_t)(k+2)*Hh];
      float4 w3 = *(const float4*)&Wg[(size_t)(k+3)*Hh];
      float4 x0 = *(const float4*)&xr[0][k];
      float4 x1 = *(const float4*)&xr[1][k];
      fma4(acc[0], x0, w0, w1, w2, w3);
      fma4(acc[1], x1, w0, w1, w2, w3);
    }

    #pragma unroll
    for (int j = 0; j < 2; ++j){
      int node = nsc[j];
      if (node >= 0){
        float* op = out + (size_t)(b*Nn + node)*Hh + c0;
        atomicAdd(op+0, acc[j][0]);
        atomicAdd(op+1, acc[j][1]);
        atomicAdd(op+2, acc[j][2]);
        atomicAdd(op+3, acc[j][3]);
      }
    }
  }
}

// ------------- fused GatedFusion + GRU v7: split-K across lane pairs -------------
// 1024 blocks x 256 threads; block = 4 rows x 128 cols; thread = 1 row x 4 cols x K-half.
// lane: kh = lane>>5 (K-half), r = (lane&31)>>3, c0 = w*32 + (lane&7)*4.
// Partials combined with one __shfl_xor(.,32) per phase output.
__global__ __launch_bounds__(256, 4) void k_fuse_gru(
    const float* __restrict__ hin, const float* __restrict__ fw, const float* __restrict__ bw,
    const float* __restrict__ Ff, const float* __restrict__ bfv,
    const float* __restrict__ Wz, const float* __restrict__ Wr, const float* __restrict__ Wt,
    float* __restrict__ hout, float* __restrict__ zf, float* __restrict__ zb)
{
  __shared__ float sA[4][FPAD];   // agg exchange
  __shared__ float sR[4][FPAD];   // r*h exchange
  int tid  = threadIdx.x;
  int row0 = blockIdx.x * 4;
  int lane = tid & 63, w = tid >> 6;
  int kh   = lane >> 5;
  int l5   = lane & 31;
  int r    = l5 >> 3;
  int c0   = w*32 + (l5 & 7)*4;
  int ko   = kh*64;

  const float* __restrict__ frow = fw  + (size_t)(row0 + r)*Hh;
  const float* __restrict__ brow = bw  + (size_t)(row0 + r)*Hh;
  const float* __restrict__ hrow = hin + (size_t)(row0 + r)*Hh;
  float4 bias = *(const float4*)&bfv[c0];

  // ---- P1: af = fw@F0 + bw@F1 + (fw*bw)@F2 (each thread: its K-half) ----
  float af[4] = {0,0,0,0};
  sec64 (frow, Ff + c0,              ko, af);
  sec64 (brow, Ff + 128*Hh + c0,     ko, af);
  prod64(frow, brow, Ff + 256*Hh + c0, ko, af);
  #pragma unroll
  for (int j = 0; j < 4; ++j) af[j] += __shfl_xor(af[j], 32);

  // agg = (1-z)*fw + z*bw  -> sA  (both K-half lanes write identical values)
  {
    float4 fv = *(const float4*)&frow[c0];
    float4 bv = *(const float4*)&brow[c0];
    float bb[4]  = {bias.x, bias.y, bias.z, bias.w};
    float fvv[4] = {fv.x, fv.y, fv.z, fv.w};
    float bvv[4] = {bv.x, bv.y, bv.z, bv.w};
    float ag[4];
    #pragma unroll
    for (int j = 0; j < 4; ++j){
      float z = sigm(af[j] + bb[j]);
      ag[j] = (1.0f - z)*fvv[j] + z*bvv[j];
    }
    *(float4*)&sA[r][c0] = make_float4(ag[0], ag[1], ag[2], ag[3]);
  }

  // ---- P2: az/ar = [h|agg] @ Wz/Wr ---- (h-half before barrier overlaps it)
  float az[4] = {0,0,0,0}, ar[4] = {0,0,0,0};
  sec2_64(hrow, Wz + c0, Wr + c0, ko, az, ar);
  __syncthreads();                                   // sA (agg) visible
  sec2_64(&sA[r][0], Wz + 128*Hh + c0, Wr + 128*Hh + c0, ko, az, ar);
  #pragma unroll
  for (int j = 0; j < 4; ++j){
    az[j] += __shfl_xor(az[j], 32);
    ar[j] += __shfl_xor(ar[j], 32);
  }

  // rh = sigmoid(ar)*h -> sR ; keep z in regs
  float zz[4], hv[4];
  {
    float4 hv4 = *(const float4*)&hrow[c0];
    hv[0]=hv4.x; hv[1]=hv4.y; hv[2]=hv4.z; hv[3]=hv4.w;
    float rh[4];
    #pragma unroll
    for (int j = 0; j < 4; ++j){
      zz[j] = sigm(az[j]);
      rh[j] = sigm(ar[j]) * hv[j];
    }
    *(float4*)&sR[r][c0] = make_float4(rh[0], rh[1], rh[2], rh[3]);
  }

  // ---- P3: at = [rh|agg] @ Wt ---- (agg-half first; sR barrier after)
  float at[4] = {0,0,0,0};
  sec64(&sA[r][0], Wt + 128*Hh + c0, ko, at);
  __syncthreads();                                   // sR (rh) visible
  sec64(&sR[r][0], Wt + c0, ko, at);
  #pragma unroll
  for (int j = 0; j < 4; ++j) at[j] += __shfl_xor(at[j], 32);

  float o[4];
  #pragma unroll
  for (int j = 0; j < 4; ++j){
    float t = tanh_fast(at[j]);
    o[j] = (1.0f - zz[j])*hv[j] + zz[j]*t;
  }
  *(float4*)&hout[(size_t)(row0 + r)*Hh + c0] = make_float4(o[0], o[1], o[2], o[3]);

  // zero fw/bw rows for the next hop (block-private rows; all reads happened above)
  {
    int ir = tid >> 6, k0 = (tid & 63)*2;
    size_t g = (size_t)(row0 + ir)*Hh + k0;
    float2 zv = {0.f, 0.f};
    *(float2*)&zf[g] = zv;
    *(float2*)&zb[g] = zv;
  }
}

extern "C" void kernel_launch(void* const* d_in, const int* in_sizes, int n_in,
                              void* d_out, int out_size, void* d_ws, size_t ws_size,
                              hipStream_t stream){
  const float* node_feature = (const float*)d_in[0];
  const int*   edge_vec     = (const int*)d_in[1];
  const float* n2e          = (const float*)d_in[2];
  const float* e2n          = (const float*)d_in[3];
  const float* Wtensor      = (const float*)d_in[4];
  const float* Wz           = (const float*)d_in[5];
  const float* Wr           = (const float*)d_in[6];
  const float* Wt           = (const float*)d_in[7];
  const float* Wf           = (const float*)d_in[8];
  const float* bf           = (const float*)d_in[9];
  float* out = (float*)d_out;

  char* p = (char*)d_ws;
  int* src   = (int*)p; p += Bb*Ee*4;
  int* tgt   = (int*)p; p += Bb*Ee*4;
  int* order = (int*)p; p += Bb*Ee*4;
  int* offs  = (int*)p; p += 4096;
  float* WT  = (float*)p; p += (size_t)Tt*Hh*Hh*4;
  float* Ff  = (float*)p; p += (size_t)384*Hh*4;
  float* bwp = (float*)p; p += (size_t)Bb*Nn*Hh*4;
  float* fwp = (float*)p; p += (size_t)Bb*Nn*Hh*4;
  float* h1  = (float*)p; p += (size_t)Bb*Nn*Hh*4;

  k_extract<<<1024, 256, 0, stream>>>((const float4*)n2e, (const float4*)e2n, src, tgt);
  k_transW<<<(Tt*Hh*Hh + 255)/256, 256, 0, stream>>>(Wtensor, WT);
  k_prep<<<(384*Hh + 255)/256, 256, 0, stream>>>(Wf, Ff);
  k_sort<<<Bb, 256, 0, stream>>>(edge_vec, order, offs);
  hipMemsetAsync(bwp, 0, (size_t)2*Bb*Nn*Hh*4, stream);   // bw+fw zero (hops re-zero in epilogue)

  const float* hin = node_feature;
  float* houts[3] = { out, h1, out };
  for (int hop = 0; hop < 3; ++hop){
    k_edge_mp<<<dim3(Bb*Tt*2, 8), 256, 0, stream>>>(hin, WT, order, offs, src, tgt, bwp, fwp);
    k_fuse_gru<<<(Bb*Nn)/4, 256, 0, stream>>>(hin, fwp, bwp, Ff, bf, Wz, Wr, Wt, houts[hop], fwp, bwp);
    hin = houts[hop];
  }
}